// Round 1
// baseline (254.015 us; speedup 1.0000x reference)
//
#include <hip/hip_runtime.h>
#include <cstdint>

#define T_DIM 1024
#define NW 16          // 1024 / 64 bit-words
#define C_GAP 10
#define NEGF (-1e30f)

__device__ __forceinline__ int wmin_i(int v) {
    #pragma unroll
    for (int s = 32; s >= 1; s >>= 1) v = min(v, __shfl_xor(v, s));
    return v;
}
__device__ __forceinline__ int wmax_i(int v) {
    #pragma unroll
    for (int s = 32; s >= 1; s >>= 1) v = max(v, __shfl_xor(v, s));
    return v;
}
__device__ __forceinline__ int wsum_i(int v) {
    #pragma unroll
    for (int s = 32; s >= 1; s >>= 1) v += __shfl_xor(v, s);
    return v;
}
__device__ __forceinline__ float wmax_f(float v) {
    #pragma unroll
    for (int s = 32; s >= 1; s >>= 1) v = fmaxf(v, __shfl_xor(v, s));
    return v;
}

// One wave (64 lanes) per row. 4 waves per block.
__global__ __launch_bounds__(256) void stca_rows(const float* __restrict__ vmem,
                                                 const int* __restrict__ labels,
                                                 float* __restrict__ out,      // [1 + BN]
                                                 float* __restrict__ partial,  // [gridDim.x]
                                                 int N)
{
    __shared__ float red[4];

    const int wid  = threadIdx.x >> 6;
    const int lane = threadIdx.x & 63;
    const int row  = (blockIdx.x << 2) | wid;
    const int b    = row / N;
    const int n    = row - b * N;

    const float* vrow = vmem + (size_t)row * T_DIM;

    // ---- load row: lane l holds t = w*64 + l, w = 0..15 (registers, read once)
    float val[NW];
    float maxall = NEGF;
    #pragma unroll
    for (int w = 0; w < NW; ++w) {
        val[w] = vrow[(w << 6) + lane];
        maxall = fmaxf(maxall, val[w]);
    }
    maxall = wmax_f(maxall);

    // ---- spike bitmask: word w bit l == spike at t = w*64 + l  (uniform per wave)
    uint64_t m[NW];
    #pragma unroll
    for (int w = 0; w < NW; ++w)
        m[w] = __ballot(val[w] >= 0.0f);

    // ---- cluster-start mask: spike & no spike in previous C_GAP steps
    // window bit t = OR of mask bits [t-10, t-1] (carry from previous word).
    // Also grab "my word" per lane (lane&15 owns word w) via unrolled select.
    int nclust = 0;
    uint64_t mw = 0, sw = 0;          // per-lane: mask word / start word owned
    const int myw = lane & 15;
    #pragma unroll
    for (int w = 0; w < NW; ++w) {
        uint64_t P = (w == 0) ? 0ull : m[w - 1];
        uint64_t win = 0;
        #pragma unroll
        for (int sft = 1; sft <= C_GAP; ++sft)
            win |= (m[w] << sft) | (P >> (64 - sft));
        uint64_t st = m[w] & ~win;
        nclust += __popcll(st);
        if (myw == w) { mw = m[w]; sw = st; }
    }

    const float target = (labels[b] == n) ? 1.0f : 0.0f;
    float contrib = 0.0f;

    if (nclust == 0) {
        // target > nc  <=> target==1 and no spikes -> loss -= max over all t
        if (target > 0.5f) contrib = -maxall;
    } else {
        const int base = myw << 6;

        // first start = min over words of lowest start bit
        int cand = sw ? (base + (__ffsll((unsigned long long)sw) - 1)) : T_DIM;
        int s = wmin_i(cand);

        int min_size = 1 << 30, min_f = 0, min_l = 0;
        while (s < T_DIM) {
            // ---- next start strictly after s (or T)
            int d = s - base;   // start bits with in-word pos > d
            uint64_t gt = (d < 0) ? ~0ull : ((d >= 63) ? 0ull : ~((2ull << d) - 1));
            uint64_t cb = sw & gt;
            int cn = cb ? (base + (__ffsll((unsigned long long)cb) - 1)) : T_DIM;
            int e = wmin_i(cn);

            // ---- spikes in [s, e): per-word range mask
            int lo = s - base; lo = lo < 0 ? 0 : (lo > 64 ? 64 : lo);
            int hi = e - base; hi = hi < 0 ? 0 : (hi > 64 ? 64 : hi);
            uint64_t below_hi = (hi >= 64) ? ~0ull : ((1ull << hi) - 1ull);
            uint64_t below_lo = (lo >= 64) ? ~0ull : ((1ull << lo) - 1ull);
            uint64_t mb = mw & below_hi & ~below_lo;

            int size = wsum_i(__popcll(mb)) >> 2;   // 4 lanes duplicate each word
            int lp = mb ? (base + 63 - __clzll((long long)mb)) : -1;
            int last = wmax_i(lp);

            if (size < min_size) { min_size = size; min_f = s; min_l = last; }
            s = e;
        }

        // ---- max of v over [min_f, min_l] (register values, wave reduce)
        float pmax = NEGF;
        #pragma unroll
        for (int w = 0; w < NW; ++w) {
            int t = (w << 6) + lane;
            pmax = fmaxf(pmax, (t >= min_f && t <= min_l) ? val[w] : NEGF);
        }
        pmax = wmax_f(pmax);

        if (target < (float)nclust) contrib = pmax;
        // target > nclust impossible here (nclust >= 1, target <= 1)
    }

    if (lane == 0) {
        out[1 + row] = (float)nclust;   // spike_output
        red[wid] = contrib;
    }
    __syncthreads();
    if (threadIdx.x == 0)
        partial[blockIdx.x] = red[0] + red[1] + red[2] + red[3];
}

__global__ __launch_bounds__(256) void reduce_partials(const float* __restrict__ partial,
                                                       int n, float* __restrict__ out)
{
    float s = 0.0f;
    for (int i = threadIdx.x; i < n; i += 256) s += partial[i];
    #pragma unroll
    for (int k = 32; k >= 1; k >>= 1) s += __shfl_xor(s, k);
    __shared__ float red[4];
    const int wid = threadIdx.x >> 6, lane = threadIdx.x & 63;
    if (lane == 0) red[wid] = s;
    __syncthreads();
    if (threadIdx.x == 0) out[0] = red[0] + red[1] + red[2] + red[3];
}

extern "C" void kernel_launch(void* const* d_in, const int* in_sizes, int n_in,
                              void* d_out, int out_size, void* d_ws, size_t ws_size,
                              hipStream_t stream)
{
    const float* vmem   = (const float*)d_in[0];
    // d_in[1] (vlastmem) is unused by the reference forward
    const int*   labels = (const int*)d_in[2];
    float* out     = (float*)d_out;
    float* partial = (float*)d_ws;

    const int BN = in_sizes[0] / T_DIM;   // 32768
    const int B  = in_sizes[2];           // 128
    const int N  = BN / B;                // 256
    const int blocks = BN >> 2;           // 4 rows (waves) per block

    stca_rows<<<blocks, 256, 0, stream>>>(vmem, labels, out, partial, N);
    reduce_partials<<<1, 256, 0, stream>>>(partial, blocks, out);
}

// Round 3
// 247.012 us; speedup vs baseline: 1.0284x; 1.0284x over previous
//
#include <hip/hip_runtime.h>
#include <cstdint>

#define T_DIM 1024
#define C_GAP 10
#define NEGF (-1e30f)

__device__ __forceinline__ int wmin_i(int v) {
    #pragma unroll
    for (int s = 32; s >= 1; s >>= 1) v = min(v, __shfl_xor(v, s));
    return v;
}
__device__ __forceinline__ int wmax_i(int v) {
    #pragma unroll
    for (int s = 32; s >= 1; s >>= 1) v = max(v, __shfl_xor(v, s));
    return v;
}
__device__ __forceinline__ int wsum_i(int v) {
    #pragma unroll
    for (int s = 32; s >= 1; s >>= 1) v += __shfl_xor(v, s);
    return v;
}
__device__ __forceinline__ float wmax_f(float v) {
    #pragma unroll
    for (int s = 32; s >= 1; s >>= 1) v = fmaxf(v, __shfl_xor(v, s));
    return v;
}

// One wave per row; lane l owns t in [16l, 16l+16). 4 waves / block.
__global__ __launch_bounds__(256) void stca_rows(const float* __restrict__ vmem,
                                                 const int* __restrict__ labels,
                                                 float* __restrict__ out,      // [1 + BN]
                                                 float* __restrict__ partial,  // [gridDim.x]
                                                 int N)
{
    __shared__ float red[4];

    const int wid  = threadIdx.x >> 6;
    const int lane = threadIdx.x & 63;
    const int row  = (blockIdx.x << 2) | wid;
    const int b    = row / N;
    const int n    = row - b * N;
    const int base = lane << 4;

    const float4* vrow = (const float4*)(vmem + (size_t)row * T_DIM);

    // ---- 16 values per lane, 16B vector loads (stride 64B per lane)
    union { float4 q[4]; float f[16]; } u;
    #pragma unroll
    for (int c = 0; c < 4; ++c) u.q[c] = vrow[(lane << 2) + c];

    float maxlane = NEGF;
    #pragma unroll
    for (int j = 0; j < 16; ++j) maxlane = fmaxf(maxlane, u.f[j]);

    // ---- per-lane 16-bit spike mask, bit j == spike at t = 16*lane + j
    uint32_t x = 0;
    #pragma unroll
    for (int j = 0; j < 16; ++j) x |= (u.f[j] >= 0.0f) ? (1u << j) : 0u;

    // ---- window OR over previous C_GAP=10 steps (needs prev lane's 16 bits)
    uint32_t prev = __shfl_up(x, 1);
    if (lane == 0) prev = 0u;
    uint32_t z  = (x << 16) | prev;
    uint32_t s1 = z << 1;
    uint32_t s2 = s1 | (s1 << 1);          // shifts 1..2
    uint32_t s4 = s2 | (s2 << 2);          // 1..4
    uint32_t s8 = s4 | (s4 << 4);          // 1..8
    uint32_t sA = s8 | (s2 << 8);          // 1..10
    uint32_t start = x & ~(sA >> 16) & 0xFFFFu;

    const int nclust = wsum_i(__popc(start));
    const float target = (labels[b] == n) ? 1.0f : 0.0f;

    float contrib = 0.0f;
    if (nclust == 0) {
        if (target > 0.5f) contrib = -wmax_f(maxlane);   // target > nc -> -max(v)
    } else if (target < (float)nclust) {
        // ---- enumerate clusters in time order, track smallest (first on ties)
        int cand = start ? (base + __ffs(start) - 1) : T_DIM;
        int s = wmin_i(cand);

        int min_size = 1 << 30, min_f = 0, min_l = 0;
        while (s < T_DIM) {
            // next start strictly after s
            int rel = s - base;
            uint32_t gt = (rel < 0) ? 0xFFFFu : ((rel >= 15) ? 0u : ((0xFFFFu << (rel + 1)) & 0xFFFFu));
            uint32_t cb = start & gt;
            int e = wmin_i(cb ? (base + __ffs(cb) - 1) : T_DIM);

            // spikes within [s, e)
            int lo = s - base; lo = lo < 0 ? 0 : (lo > 16 ? 16 : lo);
            int hi = e - base; hi = hi < 0 ? 0 : (hi > 16 ? 16 : hi);
            uint32_t mb = x & ((1u << hi) - 1u) & ~((1u << lo) - 1u);

            int size = wsum_i(__popc(mb));
            int last = wmax_i(mb ? (base + 31 - __clz(mb)) : -1);

            if (size < min_size) { min_size = size; min_f = s; min_l = last; }
            s = e;
        }

        // max v over the smallest cluster's span [min_f, min_l]
        float pm = NEGF;
        #pragma unroll
        for (int j = 0; j < 16; ++j) {
            int t = base + j;
            pm = (t >= min_f && t <= min_l) ? fmaxf(pm, u.f[j]) : pm;
        }
        contrib = wmax_f(pm);
    }

    if (lane == 0) {
        out[1 + row] = (float)nclust;   // spike_output
        red[wid] = contrib;
    }
    __syncthreads();
    if (threadIdx.x == 0)
        partial[blockIdx.x] = red[0] + red[1] + red[2] + red[3];
}

__global__ __launch_bounds__(256) void reduce_partials(const float* __restrict__ partial,
                                                       int n, float* __restrict__ out)
{
    float a0 = 0.f, a1 = 0.f, a2 = 0.f, a3 = 0.f;
    for (int i = threadIdx.x; i < n; i += 1024) {
        a0 += partial[i];
        a1 += (i + 256 < n) ? partial[i + 256] : 0.f;
        a2 += (i + 512 < n) ? partial[i + 512] : 0.f;
        a3 += (i + 768 < n) ? partial[i + 768] : 0.f;
    }
    float s = (a0 + a1) + (a2 + a3);
    #pragma unroll
    for (int k = 32; k >= 1; k >>= 1) s += __shfl_xor(s, k);
    __shared__ float red[4];
    const int wid = threadIdx.x >> 6, lane = threadIdx.x & 63;
    if (lane == 0) red[wid] = s;
    __syncthreads();
    if (threadIdx.x == 0) out[0] = red[0] + red[1] + red[2] + red[3];
}

extern "C" void kernel_launch(void* const* d_in, const int* in_sizes, int n_in,
                              void* d_out, int out_size, void* d_ws, size_t ws_size,
                              hipStream_t stream)
{
    const float* vmem   = (const float*)d_in[0];
    // d_in[1] (vlastmem) unused by the reference forward
    const int*   labels = (const int*)d_in[2];
    float* out     = (float*)d_out;
    float* partial = (float*)d_ws;

    const int BN = in_sizes[0] / T_DIM;   // 32768
    const int B  = in_sizes[2];           // 128
    const int N  = BN / B;                // 256
    const int blocks = BN >> 2;           // 4 rows (waves) per block

    stca_rows<<<blocks, 256, 0, stream>>>(vmem, labels, out, partial, N);
    reduce_partials<<<1, 256, 0, stream>>>(partial, blocks, out);
}